// Round 2
// baseline (11226.329 us; speedup 1.0000x reference)
//
#include <hip/hip_runtime.h>

// Problem constants
#define NROWS 16384
#define DIN   1024
#define DH    4096
#define DZ    256
#define KCB   4096

// ---------------------------------------------------------------------------
// init: zero the loss accumulator (ws is poisoned 0xAA before every launch)
__global__ void k_init(float* loss) {
    if (threadIdx.x == 0) *loss = 0.0f;
}

// ---------------------------------------------------------------------------
// Generic fp32 GEMM: C = A[M,K] @ B[K,N] + bias[N], optional ReLU.
// Tile 128x128, BK=16, 256 threads, 8x8 outputs/thread.
// M,N multiples of 128; K multiple of 16.
// LDS: 16*132*4 + 16*128*4 = 16.6 KB
template <int RELU>
__global__ __launch_bounds__(256)
void k_gemm_bias(const float* __restrict__ A, const float* __restrict__ B,
                 const float* __restrict__ bias, float* __restrict__ C,
                 int M, int N, int K) {
    __shared__ float As[16][132];   // [k][m], padded
    __shared__ float Bs[16][128];   // [k][n]

    const int tid = threadIdx.x;
    const int tx = tid & 15;        // -> n
    const int ty = tid >> 4;        // -> m
    const long m0 = (long)blockIdx.y * 128;
    const long n0 = (long)blockIdx.x * 128;

    float acc[8][8];
#pragma unroll
    for (int i = 0; i < 8; i++)
#pragma unroll
        for (int j = 0; j < 8; j++) acc[i][j] = 0.0f;

    for (int k0 = 0; k0 < K; k0 += 16) {
#pragma unroll
        for (int s = 0; s < 2; s++) {
            int idx = tid + 256 * s;
            int ar  = idx >> 2;          // 0..127
            int akg = idx & 3;           // 0..3
            float4 av = *(const float4*)(A + (m0 + ar) * (long)K + k0 + akg * 4);
            As[akg * 4 + 0][ar] = av.x;
            As[akg * 4 + 1][ar] = av.y;
            As[akg * 4 + 2][ar] = av.z;
            As[akg * 4 + 3][ar] = av.w;

            int br  = idx >> 5;          // 0..15
            int bcg = idx & 31;          // 0..31
            float4 bv = *(const float4*)(B + (long)(k0 + br) * N + n0 + bcg * 4);
            *(float4*)(&Bs[br][bcg * 4]) = bv;
        }
        __syncthreads();

#pragma unroll
        for (int kk = 0; kk < 16; kk++) {
            float a[8], b[8];
            *(float4*)(a)     = *(const float4*)(&As[kk][ty * 8]);
            *(float4*)(a + 4) = *(const float4*)(&As[kk][ty * 8 + 4]);
            *(float4*)(b)     = *(const float4*)(&Bs[kk][tx * 8]);
            *(float4*)(b + 4) = *(const float4*)(&Bs[kk][tx * 8 + 4]);
#pragma unroll
            for (int i = 0; i < 8; i++)
#pragma unroll
                for (int j = 0; j < 8; j++)
                    acc[i][j] = fmaf(a[i], b[j], acc[i][j]);
        }
        __syncthreads();
    }

#pragma unroll
    for (int i = 0; i < 8; i++) {
        long row = m0 + ty * 8 + i;
#pragma unroll
        for (int jg = 0; jg < 2; jg++) {
            long col = n0 + tx * 8 + jg * 4;
            float4 v;
            v.x = acc[i][jg * 4 + 0] + bias[col + 0];
            v.y = acc[i][jg * 4 + 1] + bias[col + 1];
            v.z = acc[i][jg * 4 + 2] + bias[col + 2];
            v.w = acc[i][jg * 4 + 3] + bias[col + 3];
            if (RELU) {
                v.x = fmaxf(v.x, 0.0f); v.y = fmaxf(v.y, 0.0f);
                v.z = fmaxf(v.z, 0.0f); v.w = fmaxf(v.w, 0.0f);
            }
            *(float4*)(C + row * (long)N + col) = v;
        }
    }
}

// ---------------------------------------------------------------------------
// Row squared norms: out[r] = sum(X[r,:]^2). ncols multiple of 256.
__global__ void k_row_sq_norms(const float* __restrict__ X, float* __restrict__ out,
                               int ncols, int nrows) {
    const int wave = threadIdx.x >> 6;
    const int lane = threadIdx.x & 63;
    const long row = (long)blockIdx.x * 4 + wave;
    if (row >= nrows) return;
    const float* p = X + row * (long)ncols;
    float s = 0.0f;
    for (int c = lane * 4; c < ncols; c += 256) {
        float4 v = *(const float4*)(p + c);
        s += v.x * v.x + v.y * v.y + v.z * v.z + v.w * v.w;
    }
#pragma unroll
    for (int off = 32; off > 0; off >>= 1) s += __shfl_down(s, off, 64);
    if (lane == 0) out[row] = s;
}

// ---------------------------------------------------------------------------
// Distances + argmin + loss. d = z2[r] + c2[k] - 2*dot(z_r, c_k).
// 32 rows per block (LDS: 32*260*4 + 16*68*4 = 37.6 KB < 64 KB).
// First-min tie-break matches jnp.argmin.
__global__ __launch_bounds__(256)
void k_dist_argmin(const float* __restrict__ Z, const float* __restrict__ CB,
                   const float* __restrict__ Z2, const float* __restrict__ C2,
                   int* __restrict__ words, float* __restrict__ loss) {
    __shared__ float Lz[32][260];   // 32 z-rows x 256, padded
    __shared__ float Cs[16][68];    // [d][k] transposed codebook tile, padded

    const int tid = threadIdx.x;
    const int tx = tid & 15;        // -> k (4 each, 64 k per tile)
    const int ty = tid >> 4;        // 0..15 -> rows (2 each)
    const long r0 = (long)blockIdx.x * 32;

    // Stage 32 z rows (8K floats = 2048 float4; 8 per thread)
#pragma unroll
    for (int s = 0; s < 8; s++) {
        int idx = tid + 256 * s;
        int row = idx >> 6;         // 0..31
        int dg  = idx & 63;         // 0..63
        float4 v = *(const float4*)(Z + (r0 + row) * (long)DZ + dg * 4);
        *(float4*)(&Lz[row][dg * 4]) = v;
    }
    __syncthreads();

    float z2v[2];
#pragma unroll
    for (int i = 0; i < 2; i++) z2v[i] = Z2[r0 + ty * 2 + i];

    float best[2];
    int   bidx[2];
#pragma unroll
    for (int i = 0; i < 2; i++) { best[i] = 3.4e38f; bidx[i] = 0; }

    for (int k0 = 0; k0 < KCB; k0 += 64) {
        float acc[2][4];
#pragma unroll
        for (int i = 0; i < 2; i++)
#pragma unroll
            for (int j = 0; j < 4; j++) acc[i][j] = 0.0f;

        for (int d0 = 0; d0 < DZ; d0 += 16) {
            // Stage codebook tile transposed: Cs[d][k]
            {
                int kk = tid >> 2;   // 0..63
                int dg = tid & 3;    // 0..3
                float4 v = *(const float4*)(CB + (long)(k0 + kk) * DZ + d0 + dg * 4);
                Cs[dg * 4 + 0][kk] = v.x;
                Cs[dg * 4 + 1][kk] = v.y;
                Cs[dg * 4 + 2][kk] = v.z;
                Cs[dg * 4 + 3][kk] = v.w;
            }
            __syncthreads();
#pragma unroll
            for (int dd = 0; dd < 16; dd++) {
                float b[4];
                *(float4*)b = *(const float4*)(&Cs[dd][tx * 4]);
#pragma unroll
                for (int i = 0; i < 2; i++) {
                    float a = Lz[ty * 2 + i][d0 + dd];
#pragma unroll
                    for (int j = 0; j < 4; j++)
                        acc[i][j] = fmaf(a, b[j], acc[i][j]);
                }
            }
            __syncthreads();
        }

#pragma unroll
        for (int i = 0; i < 2; i++) {
            float lmin = z2v[i] + C2[k0 + tx * 4 + 0] - 2.0f * acc[i][0];
            int   lidx = k0 + tx * 4 + 0;
#pragma unroll
            for (int j = 1; j < 4; j++) {
                float d = z2v[i] + C2[k0 + tx * 4 + j] - 2.0f * acc[i][j];
                int   kidx = k0 + tx * 4 + j;
                if (d < lmin) { lmin = d; lidx = kidx; }
            }
            // reduce across the 16 tx lanes (xor stays inside the 16-group)
#pragma unroll
            for (int off = 8; off > 0; off >>= 1) {
                float ov = __shfl_xor(lmin, off, 64);
                int   oi = __shfl_xor(lidx, off, 64);
                if (ov < lmin || (ov == lmin && oi < lidx)) { lmin = ov; lidx = oi; }
            }
            if (lmin < best[i]) { best[i] = lmin; bidx[i] = lidx; }
        }
    }

    if (tx == 0) {
        float sum = 0.0f;
#pragma unroll
        for (int i = 0; i < 2; i++) {
            long r = r0 + ty * 2 + i;
            words[r] = bidx[i];
            sum += best[i];
        }
        atomicAdd(loss, sum);
    }
}

// ---------------------------------------------------------------------------
// Gather quantized rows + write final loss (= z_loss + c_loss = 2 * sum)
__global__ void k_output(const float* __restrict__ CB, const int* __restrict__ words,
                         const float* __restrict__ loss, float* __restrict__ out) {
    const long n = blockIdx.x;
    const int t = threadIdx.x;      // 64 threads, one float4 each
    const int w = words[n];
    float4 v = *(const float4*)(CB + (long)w * DZ + t * 4);
    *(float4*)(out + n * (long)DZ + t * 4) = v;
    if (n == 0 && t == 0) out[(long)NROWS * DZ] = 2.0f * loss[0];
}

// ---------------------------------------------------------------------------
extern "C" void kernel_launch(void* const* d_in, const int* in_sizes, int n_in,
                              void* d_out, int out_size, void* d_ws, size_t ws_size,
                              hipStream_t stream) {
    const float* x  = (const float*)d_in[0];
    const float* W1 = (const float*)d_in[1];
    const float* b1 = (const float*)d_in[2];
    const float* W2 = (const float*)d_in[3];
    const float* b2 = (const float*)d_in[4];
    const float* W3 = (const float*)d_in[5];
    const float* b3 = (const float*)d_in[6];
    const float* cb = (const float*)d_in[7];
    float* out = (float*)d_out;

    // --- workspace layout: fixed region first, then two chunk buffers ---
    float* ws = (float*)d_ws;
    const size_t Z_ELEMS = (size_t)NROWS * DZ;            // 4,194,304
    float* z     = ws;
    float* z2    = z  + Z_ELEMS;
    float* c2    = z2 + NROWS;
    int*   words = (int*)(c2 + KCB);
    float* loss  = (float*)(words + NROWS);
    const size_t FIXED = Z_ELEMS + NROWS + KCB + NROWS + 1;
    float* chunk = loss + 1;

    // rows per chunk: largest multiple of 128 such that 2*rc*DH floats fit
    size_t total_f = ws_size / sizeof(float);
    size_t avail   = (total_f > FIXED) ? (total_f - FIXED) : 0;
    size_t rc      = avail / (2 * (size_t)DH);
    rc = (rc / 128) * 128;
    if (rc > NROWS) rc = NROWS;
    if (rc < 128)   rc = 128;     // minimum viable; below this nothing fits anyway

    k_init<<<1, 64, 0, stream>>>(loss);

    for (size_t r0 = 0; r0 < NROWS; r0 += rc) {
        size_t rows = NROWS - r0;
        if (rows > rc) rows = rc;             // always a multiple of 128
        float* h1 = chunk;
        float* h2 = chunk + rc * (size_t)DH;

        // h1 = relu(x_chunk @ W1 + b1)
        k_gemm_bias<1><<<dim3(DH / 128, rows / 128), 256, 0, stream>>>(
            x + r0 * DIN, W1, b1, h1, (int)rows, DH, DIN);
        // h2 = h1 @ W2 + b2
        k_gemm_bias<0><<<dim3(DH / 128, rows / 128), 256, 0, stream>>>(
            h1, W2, b2, h2, (int)rows, DH, DH);
        // z_chunk = h2 @ W3 + b3
        k_gemm_bias<0><<<dim3(DZ / 128, rows / 128), 256, 0, stream>>>(
            h2, W3, b3, z + r0 * DZ, (int)rows, DZ, DH);
    }

    k_row_sq_norms<<<NROWS / 4, 256, 0, stream>>>(z, z2, DZ, NROWS);
    k_row_sq_norms<<<KCB / 4, 256, 0, stream>>>(cb, c2, DZ, KCB);

    k_dist_argmin<<<NROWS / 32, 256, 0, stream>>>(z, cb, z2, c2, words, loss);

    k_output<<<NROWS, 64, 0, stream>>>(cb, words, loss, out);
}

// Round 4
// 4710.541 us; speedup vs baseline: 2.3832x; 2.3832x over previous
//
#include <hip/hip_runtime.h>

#define NROWS 16384
#define DIN   1024
#define DH    4096
#define DZ    256
#define KCB   4096

typedef _Float16 f16x8 __attribute__((ext_vector_type(8)));
typedef _Float16 f16x4 __attribute__((ext_vector_type(4)));
typedef float    f32x4 __attribute__((ext_vector_type(4)));

#define INV4096 2.44140625e-4f
#define F16_MIN_NORMAL 6.103515625e-05f

struct Split { _Float16 h, l; };

// Split v into h + l/4096 with h, l normal-or-zero f16 (denormal-safe).
__device__ inline Split splitf(float v) {
    _Float16 hh = (_Float16)v;
    float hf = (float)hh;
    if (fabsf(hf) < F16_MIN_NORMAL) { hh = (_Float16)0.0f; hf = 0.0f; }
    Split s;
    s.h = hh;
    s.l = (_Float16)((v - hf) * 4096.0f);
    return s;
}

__device__ inline void gload_lds16(const void* g, void* l) {
    __builtin_amdgcn_global_load_lds(
        (const __attribute__((address_space(1))) void*)g,
        (__attribute__((address_space(3))) void*)l, 16, 0, 0);
}

// ---------------------------------------------------------------------------
__global__ void k_init_best(unsigned long long* best) {
    int i = blockIdx.x * 256 + threadIdx.x;
    if (i < NROWS) best[i] = 0xFFFFFFFFFFFFFFFFULL;
}

// Element-wise fp32 -> split f16 pair. n multiple of 1024.
__global__ void k_esplit(const float* __restrict__ X, _Float16* __restrict__ H,
                         _Float16* __restrict__ L, size_t n) {
    size_t i = ((size_t)blockIdx.x * 256 + threadIdx.x) * 4;
    if (i >= n) return;
    float4 v = *(const float4*)(X + i);
    f16x4 hv, lv;
    Split s0 = splitf(v.x), s1 = splitf(v.y), s2 = splitf(v.z), s3 = splitf(v.w);
    hv[0] = s0.h; hv[1] = s1.h; hv[2] = s2.h; hv[3] = s3.h;
    lv[0] = s0.l; lv[1] = s1.l; lv[2] = s2.l; lv[3] = s3.l;
    *(f16x4*)(H + i) = hv;
    *(f16x4*)(L + i) = lv;
}

// Transpose + split: B[K][N] fp32 -> Th/Tl [N][K] f16. K,N multiples of 32.
__global__ void k_tsplit(const float* __restrict__ B, _Float16* __restrict__ Th,
                         _Float16* __restrict__ Tl, int K, int N) {
    __shared__ float tile[32][33];
    const int k0 = blockIdx.x * 32, n0 = blockIdx.y * 32;
    const int tx = threadIdx.x, ty = threadIdx.y;   // block (32,8)
#pragma unroll
    for (int i = 0; i < 4; i++)
        tile[ty + i * 8][tx] = B[(size_t)(k0 + ty + i * 8) * N + n0 + tx];
    __syncthreads();
#pragma unroll
    for (int i = 0; i < 4; i++) {
        float v = tile[tx][ty + i * 8];
        Split s = splitf(v);
        size_t o = (size_t)(n0 + ty + i * 8) * K + k0 + tx;
        Th[o] = s.h; Tl[o] = s.l;
    }
}

// ---------------------------------------------------------------------------
// Split-precision f16 MFMA GEMM. C = A[M,K] @ Bt[N,K]^T (+bias).
// A given as Ah/Al [M][K], B as Bh/Bl [N][K] (pre-transposed), all f16,
// value = h + l/4096. 128x128 tile, BK=32, 4 waves, 16x16x32 MFMA.
// MODE 0: Ch/Cl = split(relu(C+bias));  MODE 1: split(C+bias)
// MODE 2: Cf = C+bias (fp32) AND Ch/Cl = split
// MODE 3: distance epilogue: d = Z2[m] + C2[n] - 2*C; packed atomicMin(best)
template <int MODE>
__global__ __launch_bounds__(256, 2)
void k_gemm_split(const _Float16* __restrict__ Ah, const _Float16* __restrict__ Al,
                  const _Float16* __restrict__ Bh, const _Float16* __restrict__ Bl,
                  const float* __restrict__ bias,
                  _Float16* __restrict__ Ch, _Float16* __restrict__ Cl,
                  float* __restrict__ Cf,
                  const float* __restrict__ Z2, const float* __restrict__ C2,
                  unsigned long long* __restrict__ best,
                  int M, int N, int K) {
    __shared__ __align__(16) _Float16 sAh[128 * 32];
    __shared__ __align__(16) _Float16 sAl[128 * 32];
    __shared__ __align__(16) _Float16 sBh[128 * 32];
    __shared__ __align__(16) _Float16 sBl[128 * 32];

    const int tid  = threadIdx.x;
    const int w    = tid >> 6;
    const int l    = tid & 63;
    const int wm   = w >> 1, wn = w & 1;
    const int quad = l >> 4, lcol = l & 15;
    const long m0 = (long)blockIdx.y * 128;
    const long n0 = (long)blockIdx.x * 128;

    // staging assignment: wave w stages one tile
    const _Float16* gsrc; _Float16* ldst; long rbase;
    if      (w == 0) { gsrc = Ah; ldst = sAh; rbase = m0; }
    else if (w == 1) { gsrc = Al; ldst = sAl; rbase = m0; }
    else if (w == 2) { gsrc = Bh; ldst = sBh; rbase = n0; }
    else             { gsrc = Bl; ldst = sBl; rbase = n0; }
    const _Float16* gbase = gsrc + (rbase + (l >> 2)) * (size_t)K + (l & 3) * 8;

    f32x4 acc_h[4][4], acc_x[4][4];
#pragma unroll
    for (int i = 0; i < 4; i++)
#pragma unroll
        for (int j = 0; j < 4; j++) {
            acc_h[i][j] = (f32x4){0.f, 0.f, 0.f, 0.f};
            acc_x[i][j] = (f32x4){0.f, 0.f, 0.f, 0.f};
        }

    for (int k0 = 0; k0 < K; k0 += 32) {
        // stage 128x32 f16 tile per buffer: each wave does 8 lds-loads of 1KB
#pragma unroll
        for (int u = 0; u < 8; u++)
            gload_lds16(gbase + k0 + (size_t)u * 16 * K, ldst + u * 16 * 32);
        __syncthreads();

        f16x8 fa_h[4], fa_l[4], fb_h[4], fb_l[4];
#pragma unroll
        for (int fi = 0; fi < 4; fi++) {
            const int o = (wm * 64 + fi * 16 + lcol) * 32 + quad * 8;
            fa_h[fi] = *(const f16x8*)(sAh + o);
            fa_l[fi] = *(const f16x8*)(sAl + o);
        }
#pragma unroll
        for (int fj = 0; fj < 4; fj++) {
            const int o = (wn * 64 + fj * 16 + lcol) * 32 + quad * 8;
            fb_h[fj] = *(const f16x8*)(sBh + o);
            fb_l[fj] = *(const f16x8*)(sBl + o);
        }
#pragma unroll
        for (int fi = 0; fi < 4; fi++)
#pragma unroll
            for (int fj = 0; fj < 4; fj++) {
                acc_h[fi][fj] = __builtin_amdgcn_mfma_f32_16x16x32_f16(
                    fa_h[fi], fb_h[fj], acc_h[fi][fj], 0, 0, 0);
                acc_x[fi][fj] = __builtin_amdgcn_mfma_f32_16x16x32_f16(
                    fa_h[fi], fb_l[fj], acc_x[fi][fj], 0, 0, 0);
                acc_x[fi][fj] = __builtin_amdgcn_mfma_f32_16x16x32_f16(
                    fa_l[fi], fb_h[fj], acc_x[fi][fj], 0, 0, 0);
            }
        __syncthreads();
    }

    if (MODE != 3) {
#pragma unroll
        for (int fj = 0; fj < 4; fj++) {
            const long col = n0 + wn * 64 + fj * 16 + lcol;
            const float bv = bias[col];
#pragma unroll
            for (int fi = 0; fi < 4; fi++) {
#pragma unroll
                for (int r = 0; r < 4; r++) {
                    const long row = m0 + wm * 64 + fi * 16 + quad * 4 + r;
                    float v = (acc_h[fi][fj][r] + INV4096 * acc_x[fi][fj][r]) + bv;
                    if (MODE == 0) v = fmaxf(v, 0.0f);
                    Split s = splitf(v);
                    const size_t o = (size_t)row * N + col;
                    Ch[o] = s.h; Cl[o] = s.l;
                    if (MODE == 2) Cf[o] = v;
                }
            }
        }
    } else {
        float cc2[4];
#pragma unroll
        for (int fj = 0; fj < 4; fj++)
            cc2[fj] = C2[n0 + wn * 64 + fj * 16 + lcol];
#pragma unroll
        for (int fi = 0; fi < 4; fi++) {
#pragma unroll
            for (int r = 0; r < 4; r++) {
                const long row = m0 + wm * 64 + fi * 16 + quad * 4 + r;
                const float zz = Z2[row];
                float dmin = 3.4e38f; int didx = 0x7FFFFFFF;
#pragma unroll
                for (int fj = 0; fj < 4; fj++) {
                    float accv = acc_h[fi][fj][r] + INV4096 * acc_x[fi][fj][r];
                    int col = (int)(n0 + wn * 64 + fj * 16 + lcol);
                    float d = (zz + cc2[fj]) - 2.0f * accv;
                    if (d < dmin || (d == dmin && col < didx)) { dmin = d; didx = col; }
                }
#pragma unroll
                for (int off = 1; off < 16; off <<= 1) {
                    float ov = __shfl_xor(dmin, off, 64);
                    int   oi = __shfl_xor(didx, off, 64);
                    if (ov < dmin || (ov == dmin && oi < didx)) { dmin = ov; didx = oi; }
                }
                if (lcol == 0) {
                    unsigned long long pk =
                        ((unsigned long long)__float_as_uint(dmin) << 32) |
                        (unsigned long long)(unsigned)didx;
                    atomicMin(best + row, pk);
                }
            }
        }
    }
}

// ---------------------------------------------------------------------------
__global__ void k_row_sq_norms(const float* __restrict__ X, float* __restrict__ out,
                               int ncols, int nrows) {
    const int wave = threadIdx.x >> 6;
    const int lane = threadIdx.x & 63;
    const long row = (long)blockIdx.x * 4 + wave;
    if (row >= nrows) return;
    const float* p = X + row * (long)ncols;
    float s = 0.0f;
    for (int c = lane * 4; c < ncols; c += 256) {
        float4 v = *(const float4*)(p + c);
        s += v.x * v.x + v.y * v.y + v.z * v.z + v.w * v.w;
    }
#pragma unroll
    for (int off = 32; off > 0; off >>= 1) s += __shfl_down(s, off, 64);
    if (lane == 0) out[row] = s;
}

__global__ void k_loss(const unsigned long long* __restrict__ best,
                       float* __restrict__ out) {
    __shared__ float red[256];
    float s = 0.0f;
    for (int i = threadIdx.x; i < NROWS; i += 256)
        s += __uint_as_float((unsigned)(best[i] >> 32));
    red[threadIdx.x] = s;
    __syncthreads();
    for (int st = 128; st > 0; st >>= 1) {
        if (threadIdx.x < st) red[threadIdx.x] += red[threadIdx.x + st];
        __syncthreads();
    }
    if (threadIdx.x == 0) out[(size_t)NROWS * DZ] = 2.0f * red[0];
}

__global__ void k_output(const float* __restrict__ CB,
                         const unsigned long long* __restrict__ best,
                         float* __restrict__ out) {
    const long n = blockIdx.x;
    const int t = threadIdx.x;      // 64 threads
    const int wd = (int)(unsigned)(best[n] & 0xFFFFFFFFULL);
    float4 v = *(const float4*)(CB + (size_t)wd * DZ + t * 4);
    *(float4*)(out + n * (size_t)DZ + t * 4) = v;
}

// ---------------------------------------------------------------------------
extern "C" void kernel_launch(void* const* d_in, const int* in_sizes, int n_in,
                              void* d_out, int out_size, void* d_ws, size_t ws_size,
                              hipStream_t stream) {
    const float* x  = (const float*)d_in[0];
    const float* W1 = (const float*)d_in[1];
    const float* b1 = (const float*)d_in[2];
    const float* W2 = (const float*)d_in[3];
    const float* b2 = (const float*)d_in[4];
    const float* W3 = (const float*)d_in[5];
    const float* b3 = (const float*)d_in[6];
    const float* cb = (const float*)d_in[7];
    float* out = (float*)d_out;

    // ---- workspace carve-up (bytes, 256-aligned) ----
    char* base = (char*)d_ws;
    size_t off = 0;
    auto alloc = [&](size_t bytes) -> void* {
        void* p = base + off;
        off = (off + bytes + 255) & ~(size_t)255;
        return p;
    };
    _Float16* W1tH = (_Float16*)alloc((size_t)DH * DIN * 2);
    _Float16* W1tL = (_Float16*)alloc((size_t)DH * DIN * 2);
    _Float16* W2tH = (_Float16*)alloc((size_t)DH * DH * 2);
    _Float16* W2tL = (_Float16*)alloc((size_t)DH * DH * 2);
    _Float16* W3tH = (_Float16*)alloc((size_t)DZ * DH * 2);
    _Float16* W3tL = (_Float16*)alloc((size_t)DZ * DH * 2);
    _Float16* xH   = (_Float16*)alloc((size_t)NROWS * DIN * 2);
    _Float16* xL   = (_Float16*)alloc((size_t)NROWS * DIN * 2);
    _Float16* cbH  = (_Float16*)alloc((size_t)KCB * DZ * 2);
    _Float16* cbL  = (_Float16*)alloc((size_t)KCB * DZ * 2);
    _Float16* zH   = (_Float16*)alloc((size_t)NROWS * DZ * 2);
    _Float16* zL   = (_Float16*)alloc((size_t)NROWS * DZ * 2);
    float*    zF   = (float*)alloc((size_t)NROWS * DZ * 4);
    float*    z2   = (float*)alloc((size_t)NROWS * 4);
    float*    c2   = (float*)alloc((size_t)KCB * 4);
    unsigned long long* best = (unsigned long long*)alloc((size_t)NROWS * 8);

    // chunk buffers for h1/h2 splits: 4 arrays of rc*DH f16
    size_t rem = (ws_size > off) ? (ws_size - off) : 0;
    size_t rc = rem / ((size_t)DH * 2 * 4);
    rc = (rc / 128) * 128;
    if (rc > NROWS) rc = NROWS;
    if (rc < 128)   rc = 128;
    _Float16* h1H = (_Float16*)alloc((size_t)rc * DH * 2);
    _Float16* h1L = (_Float16*)alloc((size_t)rc * DH * 2);
    _Float16* h2H = (_Float16*)alloc((size_t)rc * DH * 2);
    _Float16* h2L = (_Float16*)alloc((size_t)rc * DH * 2);

    // ---- conversions ----
    k_init_best<<<(NROWS + 255) / 256, 256, 0, stream>>>(best);
    k_esplit<<<(unsigned)((size_t)NROWS * DIN / 1024), 256, 0, stream>>>(
        x, xH, xL, (size_t)NROWS * DIN);
    k_esplit<<<(unsigned)((size_t)KCB * DZ / 1024), 256, 0, stream>>>(
        cb, cbH, cbL, (size_t)KCB * DZ);
    k_tsplit<<<dim3(DIN / 32, DH / 32), dim3(32, 8), 0, stream>>>(W1, W1tH, W1tL, DIN, DH);
    k_tsplit<<<dim3(DH / 32, DH / 32),  dim3(32, 8), 0, stream>>>(W2, W2tH, W2tL, DH, DH);
    k_tsplit<<<dim3(DH / 32, DZ / 32),  dim3(32, 8), 0, stream>>>(W3, W3tH, W3tL, DH, DZ);

    // ---- MLP (chunked over rows) ----
    for (size_t r0 = 0; r0 < NROWS; r0 += rc) {
        size_t rows = NROWS - r0;
        if (rows > rc) rows = rc;
        k_gemm_split<0><<<dim3(DH / 128, rows / 128), 256, 0, stream>>>(
            xH + r0 * DIN, xL + r0 * DIN, W1tH, W1tL, b1,
            h1H, h1L, nullptr, nullptr, nullptr, nullptr, (int)rows, DH, DIN);
        k_gemm_split<1><<<dim3(DH / 128, rows / 128), 256, 0, stream>>>(
            h1H, h1L, W2tH, W2tL, b2,
            h2H, h2L, nullptr, nullptr, nullptr, nullptr, (int)rows, DH, DH);
        k_gemm_split<2><<<dim3(DZ / 128, rows / 128), 256, 0, stream>>>(
            h2H, h2L, W3tH, W3tL, b3,
            zH + r0 * DZ, zL + r0 * DZ, zF + r0 * DZ,
            nullptr, nullptr, nullptr, (int)rows, DZ, DH);
    }

    // ---- norms + distance/argmin + outputs ----
    k_row_sq_norms<<<NROWS / 4, 256, 0, stream>>>(zF, z2, DZ, NROWS);
    k_row_sq_norms<<<KCB / 4, 256, 0, stream>>>(cb, c2, DZ, KCB);

    k_gemm_split<3><<<dim3(KCB / 128, NROWS / 128), 256, 0, stream>>>(
        zH, zL, cbH, cbL, nullptr,
        nullptr, nullptr, nullptr, z2, c2, best, NROWS, KCB, DZ);

    k_loss<<<1, 256, 0, stream>>>(best, out);
    k_output<<<NROWS, 64, 0, stream>>>(cb, best, out);
}

// Round 5
// 3133.894 us; speedup vs baseline: 3.5822x; 1.5031x over previous
//
#include <hip/hip_runtime.h>

#define NROWS 16384
#define DIN   1024
#define DH    4096
#define DZ    256
#define KCB   4096

typedef _Float16 f16x8 __attribute__((ext_vector_type(8)));
typedef _Float16 f16x4 __attribute__((ext_vector_type(4)));
typedef float    f32x4 __attribute__((ext_vector_type(4)));

#define INV4096 2.44140625e-4f
#define F16_MIN_NORMAL 6.103515625e-05f

struct Split { _Float16 h, l; };

// Split v into h + l/4096 with h, l normal-or-zero f16 (denormal-safe).
__device__ inline Split splitf(float v) {
    _Float16 hh = (_Float16)v;
    float hf = (float)hh;
    if (fabsf(hf) < F16_MIN_NORMAL) { hh = (_Float16)0.0f; hf = 0.0f; }
    Split s;
    s.h = hh;
    s.l = (_Float16)((v - hf) * 4096.0f);
    return s;
}

__device__ inline void gload_lds16(const void* g, void* l) {
    __builtin_amdgcn_global_load_lds(
        (const __attribute__((address_space(1))) void*)g,
        (__attribute__((address_space(3))) void*)l, 16, 0, 0);
}

// ---------------------------------------------------------------------------
__global__ void k_init_best(unsigned long long* best) {
    int i = blockIdx.x * 256 + threadIdx.x;
    if (i < NROWS) best[i] = 0xFFFFFFFFFFFFFFFFULL;
}

// Element-wise fp32 -> split f16 pair. n multiple of 1024.
__global__ void k_esplit(const float* __restrict__ X, _Float16* __restrict__ H,
                         _Float16* __restrict__ L, size_t n) {
    size_t i = ((size_t)blockIdx.x * 256 + threadIdx.x) * 4;
    if (i >= n) return;
    float4 v = *(const float4*)(X + i);
    f16x4 hv, lv;
    Split s0 = splitf(v.x), s1 = splitf(v.y), s2 = splitf(v.z), s3 = splitf(v.w);
    hv[0] = s0.h; hv[1] = s1.h; hv[2] = s2.h; hv[3] = s3.h;
    lv[0] = s0.l; lv[1] = s1.l; lv[2] = s2.l; lv[3] = s3.l;
    *(f16x4*)(H + i) = hv;
    *(f16x4*)(L + i) = lv;
}

// Transpose + split: B[K][N] fp32 -> Th/Tl [N][K] f16. K,N multiples of 32.
__global__ void k_tsplit(const float* __restrict__ B, _Float16* __restrict__ Th,
                         _Float16* __restrict__ Tl, int K, int N) {
    __shared__ float tile[32][33];
    const int k0 = blockIdx.x * 32, n0 = blockIdx.y * 32;
    const int tx = threadIdx.x, ty = threadIdx.y;   // block (32,8)
#pragma unroll
    for (int i = 0; i < 4; i++)
        tile[ty + i * 8][tx] = B[(size_t)(k0 + ty + i * 8) * N + n0 + tx];
    __syncthreads();
#pragma unroll
    for (int i = 0; i < 4; i++) {
        float v = tile[tx][ty + i * 8];
        Split s = splitf(v);
        size_t o = (size_t)(n0 + ty + i * 8) * K + k0 + tx;
        Th[o] = s.h; Tl[o] = s.l;
    }
}

// ---------------------------------------------------------------------------
// Split-precision f16 MFMA GEMM. C = A[M,K] @ Bt[N,K]^T (+bias).
// A as Ah/Al [M][K], B as Bh/Bl [N][K], all f16, value = h + l/4096.
// Tile BM x 128 (BM = MFRAGS*32), BK=32, 4 waves (2x2), 16x16x32 MFMA.
// MODE 0: Ch/Cl = split(relu(C+bias));  MODE 1: split(C+bias)
// MODE 2: Cf = C+bias (fp32) AND Ch/Cl = split
// MODE 3: distance epilogue: d = Z2[m] + C2[n] - 2*C; packed atomicMin(best)
template <int MODE, int MFRAGS>
__global__ __launch_bounds__(256, 2)
void k_gemm_split(const _Float16* __restrict__ Ah, const _Float16* __restrict__ Al,
                  const _Float16* __restrict__ Bh, const _Float16* __restrict__ Bl,
                  const float* __restrict__ bias,
                  _Float16* __restrict__ Ch, _Float16* __restrict__ Cl,
                  float* __restrict__ Cf,
                  const float* __restrict__ Z2, const float* __restrict__ C2,
                  unsigned long long* __restrict__ best,
                  int M, int N, int K) {
    constexpr int BM = MFRAGS * 32;               // 128 or 64
    __shared__ __align__(16) _Float16 sAh[BM * 32];
    __shared__ __align__(16) _Float16 sAl[BM * 32];
    __shared__ __align__(16) _Float16 sBh[128 * 32];
    __shared__ __align__(16) _Float16 sBl[128 * 32];

    const int tid  = threadIdx.x;
    const int w    = tid >> 6;
    const int l    = tid & 63;
    const int wm   = w >> 1, wn = w & 1;
    const int quad = l >> 4, lcol = l & 15;
    const long m0 = (long)blockIdx.y * BM;
    const long n0 = (long)blockIdx.x * 128;

    // staging assignment: wave w stages one tile
    const _Float16* gsrc; _Float16* ldst; long rbase; int nld;
    if      (w == 0) { gsrc = Ah; ldst = sAh; rbase = m0; nld = BM / 16; }
    else if (w == 1) { gsrc = Al; ldst = sAl; rbase = m0; nld = BM / 16; }
    else if (w == 2) { gsrc = Bh; ldst = sBh; rbase = n0; nld = 8; }
    else             { gsrc = Bl; ldst = sBl; rbase = n0; nld = 8; }
    const _Float16* gbase = gsrc + (rbase + (l >> 2)) * (size_t)K + (l & 3) * 8;

    f32x4 acc_h[MFRAGS][4], acc_x[MFRAGS][4];
#pragma unroll
    for (int i = 0; i < MFRAGS; i++)
#pragma unroll
        for (int j = 0; j < 4; j++) {
            acc_h[i][j] = (f32x4){0.f, 0.f, 0.f, 0.f};
            acc_x[i][j] = (f32x4){0.f, 0.f, 0.f, 0.f};
        }

    for (int k0 = 0; k0 < K; k0 += 32) {
        for (int u = 0; u < nld; u++)
            gload_lds16(gbase + k0 + (size_t)u * 16 * K, ldst + u * 16 * 32);
        __syncthreads();

        f16x8 fa_h[MFRAGS], fa_l[MFRAGS], fb_h[4], fb_l[4];
#pragma unroll
        for (int fi = 0; fi < MFRAGS; fi++) {
            const int o = (wm * (MFRAGS * 16) + fi * 16 + lcol) * 32 + quad * 8;
            fa_h[fi] = *(const f16x8*)(sAh + o);
            fa_l[fi] = *(const f16x8*)(sAl + o);
        }
#pragma unroll
        for (int fj = 0; fj < 4; fj++) {
            const int o = (wn * 64 + fj * 16 + lcol) * 32 + quad * 8;
            fb_h[fj] = *(const f16x8*)(sBh + o);
            fb_l[fj] = *(const f16x8*)(sBl + o);
        }
#pragma unroll
        for (int fi = 0; fi < MFRAGS; fi++)
#pragma unroll
            for (int fj = 0; fj < 4; fj++) {
                acc_h[fi][fj] = __builtin_amdgcn_mfma_f32_16x16x32_f16(
                    fa_h[fi], fb_h[fj], acc_h[fi][fj], 0, 0, 0);
                acc_x[fi][fj] = __builtin_amdgcn_mfma_f32_16x16x32_f16(
                    fa_h[fi], fb_l[fj], acc_x[fi][fj], 0, 0, 0);
                acc_x[fi][fj] = __builtin_amdgcn_mfma_f32_16x16x32_f16(
                    fa_l[fi], fb_h[fj], acc_x[fi][fj], 0, 0, 0);
            }
        __syncthreads();
    }

    if (MODE != 3) {
#pragma unroll
        for (int fj = 0; fj < 4; fj++) {
            const long col = n0 + wn * 64 + fj * 16 + lcol;
            const float bv = bias[col];
#pragma unroll
            for (int fi = 0; fi < MFRAGS; fi++) {
#pragma unroll
                for (int r = 0; r < 4; r++) {
                    const long row = m0 + wm * (MFRAGS * 16) + fi * 16 + quad * 4 + r;
                    float v = (acc_h[fi][fj][r] + INV4096 * acc_x[fi][fj][r]) + bv;
                    if (MODE == 0) v = fmaxf(v, 0.0f);
                    Split s = splitf(v);
                    const size_t o = (size_t)row * N + col;
                    Ch[o] = s.h; Cl[o] = s.l;
                    if (MODE == 2) Cf[o] = v;
                }
            }
        }
    } else {
        float cc2[4];
#pragma unroll
        for (int fj = 0; fj < 4; fj++)
            cc2[fj] = C2[n0 + wn * 64 + fj * 16 + lcol];
#pragma unroll
        for (int fi = 0; fi < MFRAGS; fi++) {
#pragma unroll
            for (int r = 0; r < 4; r++) {
                const long row = m0 + wm * (MFRAGS * 16) + fi * 16 + quad * 4 + r;
                const float zz = Z2[row];
                float dmin = 3.4e38f; int didx = 0x7FFFFFFF;
#pragma unroll
                for (int fj = 0; fj < 4; fj++) {
                    float accv = acc_h[fi][fj][r] + INV4096 * acc_x[fi][fj][r];
                    int col = (int)(n0 + wn * 64 + fj * 16 + lcol);
                    float d = (zz + cc2[fj]) - 2.0f * accv;
                    if (d < dmin || (d == dmin && col < didx)) { dmin = d; didx = col; }
                }
#pragma unroll
                for (int off = 1; off < 16; off <<= 1) {
                    float ov = __shfl_xor(dmin, off, 64);
                    int   oi = __shfl_xor(didx, off, 64);
                    if (ov < dmin || (ov == dmin && oi < didx)) { dmin = ov; didx = oi; }
                }
                if (lcol == 0) {
                    unsigned long long pk =
                        ((unsigned long long)__float_as_uint(dmin) << 32) |
                        (unsigned long long)(unsigned)didx;
                    atomicMin(best + row, pk);
                }
            }
        }
    }
}

// ---------------------------------------------------------------------------
__global__ void k_row_sq_norms(const float* __restrict__ X, float* __restrict__ out,
                               int ncols, int nrows) {
    const int wave = threadIdx.x >> 6;
    const int lane = threadIdx.x & 63;
    const long row = (long)blockIdx.x * 4 + wave;
    if (row >= nrows) return;
    const float* p = X + row * (long)ncols;
    float s = 0.0f;
    for (int c = lane * 4; c < ncols; c += 256) {
        float4 v = *(const float4*)(p + c);
        s += v.x * v.x + v.y * v.y + v.z * v.z + v.w * v.w;
    }
#pragma unroll
    for (int off = 32; off > 0; off >>= 1) s += __shfl_down(s, off, 64);
    if (lane == 0) out[row] = s;
}

__global__ void k_loss(const unsigned long long* __restrict__ best,
                       float* __restrict__ out) {
    __shared__ float red[256];
    float s = 0.0f;
    for (int i = threadIdx.x; i < NROWS; i += 256)
        s += __uint_as_float((unsigned)(best[i] >> 32));
    red[threadIdx.x] = s;
    __syncthreads();
    for (int st = 128; st > 0; st >>= 1) {
        if (threadIdx.x < st) red[threadIdx.x] += red[threadIdx.x + st];
        __syncthreads();
    }
    if (threadIdx.x == 0) out[(size_t)NROWS * DZ] = 2.0f * red[0];
}

__global__ void k_output(const float* __restrict__ CB,
                         const unsigned long long* __restrict__ best,
                         float* __restrict__ out) {
    const long n = blockIdx.x;
    const int t = threadIdx.x;      // 64 threads
    const int wd = (int)(unsigned)(best[n] & 0xFFFFFFFFULL);
    float4 v = *(const float4*)(CB + (size_t)wd * DZ + t * 4);
    *(float4*)(out + n * (size_t)DZ + t * 4) = v;
}

// ---------------------------------------------------------------------------
extern "C" void kernel_launch(void* const* d_in, const int* in_sizes, int n_in,
                              void* d_out, int out_size, void* d_ws, size_t ws_size,
                              hipStream_t stream) {
    const float* x  = (const float*)d_in[0];
    const float* W1 = (const float*)d_in[1];
    const float* b1 = (const float*)d_in[2];
    const float* W2 = (const float*)d_in[3];
    const float* b2 = (const float*)d_in[4];
    const float* W3 = (const float*)d_in[5];
    const float* b3 = (const float*)d_in[6];
    const float* cb = (const float*)d_in[7];
    float* out = (float*)d_out;

    // ---- workspace carve-up (bytes, 256-aligned) ----
    char* base = (char*)d_ws;
    size_t off = 0;
    auto alloc = [&](size_t bytes) -> void* {
        void* p = base + off;
        off = (off + bytes + 255) & ~(size_t)255;
        return p;
    };
    // fixed region (~120 MB): weights, codebook, z, norms, best
    _Float16* W1tH = (_Float16*)alloc((size_t)DH * DIN * 2);
    _Float16* W1tL = (_Float16*)alloc((size_t)DH * DIN * 2);
    _Float16* W2tH = (_Float16*)alloc((size_t)DH * DH * 2);
    _Float16* W2tL = (_Float16*)alloc((size_t)DH * DH * 2);
    _Float16* W3tH = (_Float16*)alloc((size_t)DZ * DH * 2);
    _Float16* W3tL = (_Float16*)alloc((size_t)DZ * DH * 2);
    _Float16* cbH  = (_Float16*)alloc((size_t)KCB * DZ * 2);
    _Float16* cbL  = (_Float16*)alloc((size_t)KCB * DZ * 2);
    _Float16* zH   = (_Float16*)alloc((size_t)NROWS * DZ * 2);
    _Float16* zL   = (_Float16*)alloc((size_t)NROWS * DZ * 2);
    float*    zF   = (float*)alloc((size_t)NROWS * DZ * 4);
    float*    z2   = (float*)alloc((size_t)NROWS * 4);
    float*    c2   = (float*)alloc((size_t)KCB * 4);
    unsigned long long* best = (unsigned long long*)alloc((size_t)NROWS * 8);

    // chunk buffers: x split (4 KB/row) + h1 split (16 KB/row) + h2 split (16 KB/row)
    size_t rem = (ws_size > off) ? (ws_size - off) : 0;
    size_t rc = rem / ((size_t)DIN * 2 * 2 + (size_t)DH * 2 * 4);
    rc = (rc / 128) * 128;
    if (rc > NROWS) rc = NROWS;
    if (rc < 128)   rc = 128;
    _Float16* xcH = (_Float16*)alloc((size_t)rc * DIN * 2);
    _Float16* xcL = (_Float16*)alloc((size_t)rc * DIN * 2);
    _Float16* h1H = (_Float16*)alloc((size_t)rc * DH * 2);
    _Float16* h1L = (_Float16*)alloc((size_t)rc * DH * 2);
    _Float16* h2H = (_Float16*)alloc((size_t)rc * DH * 2);
    _Float16* h2L = (_Float16*)alloc((size_t)rc * DH * 2);

    // ---- one-time conversions ----
    k_init_best<<<(NROWS + 255) / 256, 256, 0, stream>>>(best);
    k_esplit<<<(unsigned)((size_t)KCB * DZ / 1024), 256, 0, stream>>>(
        cb, cbH, cbL, (size_t)KCB * DZ);
    k_tsplit<<<dim3(DIN / 32, DH / 32), dim3(32, 8), 0, stream>>>(W1, W1tH, W1tL, DIN, DH);
    k_tsplit<<<dim3(DH / 32, DH / 32),  dim3(32, 8), 0, stream>>>(W2, W2tH, W2tL, DH, DH);
    k_tsplit<<<dim3(DH / 32, DZ / 32),  dim3(32, 8), 0, stream>>>(W3, W3tH, W3tL, DH, DZ);

    // ---- MLP (chunked over rows) ----
    for (size_t r0 = 0; r0 < NROWS; r0 += rc) {
        size_t rows = NROWS - r0;
        if (rows > rc) rows = rc;             // multiple of 128
        // x chunk -> split f16
        k_esplit<<<(unsigned)(rows * DIN / 1024), 256, 0, stream>>>(
            x + r0 * DIN, xcH, xcL, rows * DIN);
        // h1 = relu(x @ W1 + b1)
        k_gemm_split<0, 4><<<dim3(DH / 128, rows / 128), 256, 0, stream>>>(
            xcH, xcL, W1tH, W1tL, b1,
            h1H, h1L, nullptr, nullptr, nullptr, nullptr, (int)rows, DH, DIN);
        // h2 = h1 @ W2 + b2
        k_gemm_split<1, 4><<<dim3(DH / 128, rows / 128), 256, 0, stream>>>(
            h1H, h1L, W2tH, W2tL, b2,
            h2H, h2L, nullptr, nullptr, nullptr, nullptr, (int)rows, DH, DH);
        // z = h2 @ W3 + b3  (BM=64 variant: N=256 -> bigger grid)
        k_gemm_split<2, 2><<<dim3(DZ / 128, rows / 64), 256, 0, stream>>>(
            h2H, h2L, W3tH, W3tL, b3,
            zH + r0 * DZ, zL + r0 * DZ, zF + r0 * DZ,
            nullptr, nullptr, nullptr, (int)rows, DZ, DH);
    }

    // ---- norms + distance/argmin + outputs ----
    k_row_sq_norms<<<NROWS / 4, 256, 0, stream>>>(zF, z2, DZ, NROWS);
    k_row_sq_norms<<<KCB / 4, 256, 0, stream>>>(cb, c2, DZ, KCB);

    k_gemm_split<3, 4><<<dim3(KCB / 128, NROWS / 128), 256, 0, stream>>>(
        zH, zL, cbH, cbL, nullptr,
        nullptr, nullptr, nullptr, z2, c2, best, NROWS, KCB, DZ);

    k_loss<<<1, 256, 0, stream>>>(best, out);
    k_output<<<NROWS, 64, 0, stream>>>(cb, best, out);
}